// Round 2
// 2910.077 us; speedup vs baseline: 1.6736x; 1.6736x over previous
//
#include <hip/hip_runtime.h>
#include <hip/hip_bf16.h>
#include <math.h>

#define N_TOK   4096
#define D_MODEL 1024
#define VOCAB   32000
#define NH      16
#define DHEAD   64
#define DEPTH   4
#define PREFIX  3072
#define M_TOK   1024      /* N_TOK - PREFIX */
#define FF_DIM  4096
#define INNER   1024

typedef __hip_bfloat16 bf16;
typedef __attribute__((ext_vector_type(8))) short bf16x8;  // 8 bf16 = 4 VGPRs (MFMA A/B frag)
typedef __attribute__((ext_vector_type(4))) float f32x4;   // MFMA C/D frag

__device__ __forceinline__ unsigned short bfbits(float f) {
    union { float f; unsigned u; } x; x.f = f;
    return (unsigned short)((x.u + 0x7fffu + ((x.u >> 16) & 1u)) >> 16);  // RNE
}
__device__ __forceinline__ float2 bf2(unsigned u) {
    union { unsigned x; float f; } lo, hi;
    lo.x = u << 16; hi.x = u & 0xffff0000u;
    return make_float2(lo.f, hi.f);
}

// ---------------- residual-stream embedding (rows PREFIX..N-1), f32 ----------------
__global__ __launch_bounds__(256)
void embed_h_kernel(const int* __restrict__ x,
                    const float* __restrict__ tok,
                    const float* __restrict__ pos,
                    float* __restrict__ h)
{
    int idx = blockIdx.x * 256 + threadIdx.x;   // over M_TOK*D_MODEL
    int r = idx >> 10, c = idx & 1023;
    int row = PREFIX + r;
    h[idx] = tok[(size_t)x[row] * D_MODEL + c] + pos[(size_t)row * D_MODEL + c];
}

// ---------------- prefix embedding (rows 0..PREFIX-1), bf16 ----------------
__global__ __launch_bounds__(256)
void embed_p_kernel(const int* __restrict__ x,
                    const float* __restrict__ tok,
                    const float* __restrict__ pos,
                    bf16* __restrict__ eb)
{
    int idx = blockIdx.x * 256 + threadIdx.x;   // over PREFIX*D_MODEL
    int r = idx >> 10, c = idx & 1023;
    eb[idx] = __float2bfloat16(tok[(size_t)x[r] * D_MODEL + c] + pos[(size_t)r * D_MODEL + c]);
}

// ---------------- layernorm: f32 in, bf16 out ----------------
__global__ __launch_bounds__(256)
void ln_kernel(const float* __restrict__ src,
               const float* __restrict__ g,
               const float* __restrict__ b,
               bf16* __restrict__ dst)
{
    __shared__ float r1[256], r2[256];
    int row = blockIdx.x, tid = threadIdx.x;
    const float* xr = src + (size_t)row * D_MODEL;
    float s = 0.f, s2 = 0.f;
    for (int d = tid; d < D_MODEL; d += 256) { float v = xr[d]; s += v; s2 += v * v; }
    r1[tid] = s; r2[tid] = s2; __syncthreads();
    for (int st = 128; st > 0; st >>= 1) {
        if (tid < st) { r1[tid] += r1[tid + st]; r2[tid] += r2[tid + st]; }
        __syncthreads();
    }
    float mean = r1[0] * (1.f / D_MODEL);
    float var  = r2[0] * (1.f / D_MODEL) - mean * mean;
    float rstd = rsqrtf(var + 1e-5f);
    for (int d = tid; d < D_MODEL; d += 256)
        dst[(size_t)row * D_MODEL + d] =
            __float2bfloat16((xr[d] - mean) * rstd * g[d] + b[d]);
}

// ---------------- MFMA bf16 GEMM: C[M,N] = A[M,K](bf16) @ W[K,N](f32) ----------------
#define BM 128
#define BN 128
#define BK 32
#define ASTR 40   /* LDS row stride (elems): 32 + 8 pad, keeps 16B alignment */
__global__ __launch_bounds__(256)
void gemm_kernel(const bf16* __restrict__ A, int lda, int K,
                 const float* __restrict__ W, int ldw,
                 const float* __restrict__ bias,
                 const float* __restrict__ resid, int ldr,
                 float* __restrict__ Cf, bf16* __restrict__ Cb, int ldc,
                 int do_gelu)
{
    __shared__ bf16 As[BM * ASTR];
    __shared__ bf16 Bs[BN * ASTR];   // transposed: Bs[n][k]
    const int tid = threadIdx.x;
    const int m0 = blockIdx.y * BM, n0 = blockIdx.x * BN;
    const int ar = tid >> 1;
    const int ac = (tid & 1) << 4;
    const int bk2 = (tid >> 4) << 1;      // 0,2,..,30
    const int bn8 = (tid & 15) << 3;      // 0,8,..,120
    const int lane = tid & 63;
    const int wv   = tid >> 6;
    const int wm = (wv >> 1) * 64, wn = (wv & 1) * 64;
    const int l16 = lane & 15, quad = lane >> 4;

    f32x4 acc[4][4];
#pragma unroll
    for (int i = 0; i < 4; i++)
#pragma unroll
        for (int j = 0; j < 4; j++)
#pragma unroll
            for (int r = 0; r < 4; r++) acc[i][j][r] = 0.f;

    const unsigned short* Ag = (const unsigned short*)A + (size_t)(m0 + ar) * lda + ac;
    const float*          Wg = W + (size_t)bk2 * ldw + n0 + bn8;

    for (int k0 = 0; k0 < K; k0 += BK) {
        uint4 av0 = *(const uint4*)(Ag + k0);
        uint4 av1 = *(const uint4*)(Ag + k0 + 8);
        const float* wp = Wg + (size_t)k0 * ldw;
        float4 f0 = *(const float4*)(wp);
        float4 f1 = *(const float4*)(wp + 4);
        float4 f2 = *(const float4*)(wp + ldw);
        float4 f3 = *(const float4*)(wp + ldw + 4);
        *(uint4*)&As[ar * ASTR + ac]     = av0;
        *(uint4*)&As[ar * ASTR + ac + 8] = av1;
        float lo[8] = {f0.x, f0.y, f0.z, f0.w, f1.x, f1.y, f1.z, f1.w};
        float hi[8] = {f2.x, f2.y, f2.z, f2.w, f3.x, f3.y, f3.z, f3.w};
#pragma unroll
        for (int q = 0; q < 8; q++) {
            unsigned p = (unsigned)bfbits(lo[q]) | ((unsigned)bfbits(hi[q]) << 16);
            *(unsigned*)((unsigned short*)Bs + (size_t)(bn8 + q) * ASTR + bk2) = p;
        }
        __syncthreads();
        bf16x8 af[4], bfr[4];
#pragma unroll
        for (int i = 0; i < 4; i++)
            af[i] = *(const bf16x8*)&As[(wm + i * 16 + l16) * ASTR + quad * 8];
#pragma unroll
        for (int j = 0; j < 4; j++)
            bfr[j] = *(const bf16x8*)&Bs[(wn + j * 16 + l16) * ASTR + quad * 8];
#pragma unroll
        for (int i = 0; i < 4; i++)
#pragma unroll
            for (int j = 0; j < 4; j++)
                acc[i][j] = __builtin_amdgcn_mfma_f32_16x16x32_bf16(af[i], bfr[j],
                                                                    acc[i][j], 0, 0, 0);
        __syncthreads();
    }
#pragma unroll
    for (int i = 0; i < 4; i++) {
#pragma unroll
        for (int r = 0; r < 4; r++) {
            int mg = m0 + wm + i * 16 + quad * 4 + r;
#pragma unroll
            for (int j = 0; j < 4; j++) {
                int ng = n0 + wn + j * 16 + l16;
                float v = acc[i][j][r];
                if (do_gelu) v = 0.5f * v * (1.f + erff(v * 0.70710678118f));
                if (bias)    v += bias[ng];
                if (resid)   v += resid[(size_t)mg * ldr + ng];
                if (Cf) Cf[(size_t)mg * ldc + ng] = v;
                if (Cb) Cb[(size_t)mg * ldc + ng] = __float2bfloat16(v);
            }
        }
    }
}

// ---------------- MFMA flash attention ----------------
// One block = 64 q-rows x 1 head. 4 waves, wave w owns q-strip rows w*16..w*16+15.
// KV tiles of 64 keys: K row-major in LDS, V transposed (Vt[d][j]).
// S = Q K^T via mfma_f32_16x16x32_bf16 (2 k-chunks of 32 over DHEAD=64).
// Online softmax per row (16-lane shfl_xor reductions), P re-fragmented via
// wave-private LDS buffer, O accumulated in f32 C-frags.
#define KSTR 72   /* LDS row stride elems: 64 + 8 pad -> 144B, 16B aligned */
__global__ __launch_bounds__(256)
void attn_mfma_kernel(const bf16* __restrict__ q, int ldq,
                      const bf16* __restrict__ k, int ldk,
                      const bf16* __restrict__ v, int ldv,
                      bf16* __restrict__ out, int ldo,
                      int delta)
{
    __shared__ __align__(16) unsigned short Ks[64 * KSTR];
    __shared__ __align__(16) unsigned short Vt[64 * KSTR];       // Vt[d][j]
    __shared__ __align__(16) unsigned short Ps[4][16 * KSTR];    // per-wave P strip

    const int tid  = threadIdx.x;
    const int wv   = tid >> 6;
    const int lane = tid & 63;
    const int l16  = lane & 15, quad = lane >> 4;

    const int qt = blockIdx.x >> 4;     // NH = 16
    const int hh = blockIdx.x & 15;
    const int q0 = qt * 64;

    // Q A-frags for this wave's strip: row = q0 + wv*16 + l16
    bf16x8 aq0, aq1;
    {
        const unsigned short* qg = (const unsigned short*)q
            + (size_t)(q0 + wv * 16 + l16) * ldq + hh * DHEAD;
        aq0 = *(const bf16x8*)(qg + quad * 8);
        aq1 = *(const bf16x8*)(qg + 32 + quad * 8);
    }

    f32x4 accO[4];                       // [dj]: rows quad*4+r, col dj*16+l16
#pragma unroll
    for (int dj = 0; dj < 4; dj++)
#pragma unroll
        for (int r = 0; r < 4; r++) accO[dj][r] = 0.f;
    float mrow[4], lrow[4];
#pragma unroll
    for (int r = 0; r < 4; r++) { mrow[r] = -1e30f; lrow[r] = 0.f; }

    const int ntile = (q0 + 63 + delta) / 64 + 1;

    // staging maps
    const int sr  = tid >> 2;            // K row 0..63
    const int sc  = (tid & 3) << 4;      // K cols sc..sc+15 (two uint4 = 16 elems)
    const int vj  = tid & 63;            // V key row
    const int vd0 = (tid >> 6) << 3;     // 0,8,16,24 (and +32)

    for (int t = 0; t < ntile; t++) {
        const int j0 = t * 64;
        // stage K tile (row-major): 16 bf16 per thread = two uint4
        {
            const unsigned short* kg = (const unsigned short*)k
                + (size_t)(j0 + sr) * ldk + hh * DHEAD + sc;
            *(uint4*)&Ks[sr * KSTR + sc]     = *(const uint4*)kg;
            *(uint4*)&Ks[sr * KSTR + sc + 8] = *(const uint4*)(kg + 8);
        }
        // stage V tile transposed: Vt[d][j]
        {
            const unsigned short* vg = (const unsigned short*)v
                + (size_t)(j0 + vj) * ldv + hh * DHEAD;
            uint4 a = *(const uint4*)(vg + vd0);
            uint4 b = *(const uint4*)(vg + vd0 + 32);
            const unsigned short* ap = (const unsigned short*)&a;
            const unsigned short* bp = (const unsigned short*)&b;
#pragma unroll
            for (int e = 0; e < 8; e++) Vt[(vd0 + e) * KSTR + vj]      = ap[e];
#pragma unroll
            for (int e = 0; e < 8; e++) Vt[(vd0 + 32 + e) * KSTR + vj] = bp[e];
        }
        __syncthreads();

        // S strip = Q K^T  (4 key subtiles x 2 k-chunks)
        f32x4 s[4];
#pragma unroll
        for (int kj = 0; kj < 4; kj++) {
            f32x4 z; z[0] = z[1] = z[2] = z[3] = 0.f;
            bf16x8 b0 = *(const bf16x8*)&Ks[(kj * 16 + l16) * KSTR + quad * 8];
            bf16x8 b1 = *(const bf16x8*)&Ks[(kj * 16 + l16) * KSTR + 32 + quad * 8];
            z = __builtin_amdgcn_mfma_f32_16x16x32_bf16(aq0, b0, z, 0, 0, 0);
            z = __builtin_amdgcn_mfma_f32_16x16x32_bf16(aq1, b1, z, 0, 0, 0);
            s[kj] = z;
        }
        // scale + causal mask: allowed iff gk <= gq + delta
#pragma unroll
        for (int r = 0; r < 4; r++) {
            const int gq = q0 + wv * 16 + quad * 4 + r;
#pragma unroll
            for (int kj = 0; kj < 4; kj++) {
                const int gk = j0 + kj * 16 + l16;
                float val = s[kj][r] * 0.125f;
                s[kj][r] = (gk <= gq + delta) ? val : -1e30f;
            }
        }
        // online softmax per row (reduce across 16 lanes of the quad group)
#pragma unroll
        for (int r = 0; r < 4; r++) {
            float vmx = fmaxf(fmaxf(s[0][r], s[1][r]), fmaxf(s[2][r], s[3][r]));
#pragma unroll
            for (int sft = 1; sft < 16; sft <<= 1)
                vmx = fmaxf(vmx, __shfl_xor(vmx, sft, 64));
            const float nm = fmaxf(mrow[r], vmx);
            const float scale = __expf(mrow[r] - nm);
            mrow[r] = nm;
            float psum = 0.f;
#pragma unroll
            for (int kj = 0; kj < 4; kj++) {
                float p = __expf(s[kj][r] - nm);
                s[kj][r] = p;
                psum += p;
            }
#pragma unroll
            for (int sft = 1; sft < 16; sft <<= 1)
                psum += __shfl_xor(psum, sft, 64);
            lrow[r] = lrow[r] * scale + psum;
#pragma unroll
            for (int dj = 0; dj < 4; dj++) accO[dj][r] *= scale;
        }
        // P -> wave-private LDS (bf16), re-fragment as PV A-operand
#pragma unroll
        for (int kj = 0; kj < 4; kj++)
#pragma unroll
            for (int r = 0; r < 4; r++)
                Ps[wv][(quad * 4 + r) * KSTR + kj * 16 + l16] = bfbits(s[kj][r]);
        {
            bf16x8 pa0 = *(const bf16x8*)&Ps[wv][l16 * KSTR + quad * 8];
            bf16x8 pa1 = *(const bf16x8*)&Ps[wv][l16 * KSTR + 32 + quad * 8];
#pragma unroll
            for (int dj = 0; dj < 4; dj++) {
                bf16x8 vb0 = *(const bf16x8*)&Vt[(dj * 16 + l16) * KSTR + quad * 8];
                bf16x8 vb1 = *(const bf16x8*)&Vt[(dj * 16 + l16) * KSTR + 32 + quad * 8];
                accO[dj] = __builtin_amdgcn_mfma_f32_16x16x32_bf16(pa0, vb0, accO[dj], 0, 0, 0);
                accO[dj] = __builtin_amdgcn_mfma_f32_16x16x32_bf16(pa1, vb1, accO[dj], 0, 0, 0);
            }
        }
        __syncthreads();
    }

    // epilogue
#pragma unroll
    for (int r = 0; r < 4; r++) {
        const float inv = 1.f / lrow[r];
        const int gq = q0 + wv * 16 + quad * 4 + r;
#pragma unroll
        for (int dj = 0; dj < 4; dj++)
            out[(size_t)gq * ldo + hh * DHEAD + dj * 16 + l16] =
                __float2bfloat16(accO[dj][r] * inv);
    }
}

extern "C" void kernel_launch(void* const* d_in, const int* in_sizes, int n_in,
                              void* d_out, int out_size, void* d_ws, size_t ws_size,
                              hipStream_t stream)
{
    const int*   x        = (const int*)  d_in[0];
    const float* tok_emb  = (const float*)d_in[1];
    const float* pos_emb  = (const float*)d_in[2];
    const float* ca_ln_g  = (const float*)d_in[3];
    const float* ca_ln_b  = (const float*)d_in[4];
    const float* ca_wq    = (const float*)d_in[5];
    const float* ca_wkv   = (const float*)d_in[6];
    const float* ca_wo    = (const float*)d_in[7];
    const float* ca_bo    = (const float*)d_in[8];
    const float* cf_ln_g  = (const float*)d_in[9];
    const float* cf_ln_b  = (const float*)d_in[10];
    const float* cf_w1    = (const float*)d_in[11];
    const float* cf_w2    = (const float*)d_in[12];
    const float* la_ln_g  = (const float*)d_in[13];
    const float* la_ln_b  = (const float*)d_in[14];
    const float* la_wqkv  = (const float*)d_in[15];
    const float* la_wo    = (const float*)d_in[16];
    const float* lf_ln_g  = (const float*)d_in[17];
    const float* lf_ln_b  = (const float*)d_in[18];
    const float* lf_w1    = (const float*)d_in[19];
    const float* lf_w2    = (const float*)d_in[20];
    const float* w_logits = (const float*)d_in[21];
    float* out = (float*)d_out;

    // workspace: 34 MB
    float* h     = (float*)d_ws;                       // 1024x1024 f32
    bf16*  hb    = (bf16*)(h + (1 << 20));             // 1024x1024 bf16
    bf16*  xnb   = hb  + (1 << 20);                    // 1024x1024 bf16
    bf16*  aob   = xnb + (1 << 20);                    // 1024x1024 bf16
    bf16*  arena = aob + (1 << 20);
    bf16*  qb    = arena;                              // cross: 1024x1024
    bf16*  kvb   = arena + (1 << 20);                  // cross: 4096x2048
    bf16*  eb    = kvb + (size_t)N_TOK * 2 * INNER;    // cross: 3072x1024
    bf16*  ffb   = arena;                              // ffwd:  1024x4096
    bf16*  qkvb  = arena;                              // self:  1024x3072

    dim3 b256(256);
    auto gemm = [&](const bf16* A, int lda, int K, const float* W, int ldw,
                    const float* bias, const float* resid, int ldr,
                    float* Cf, bf16* Cb, int ldc, int Mrows, int Ncols, int gelu) {
        dim3 grid(Ncols / BN, Mrows / BM);
        gemm_kernel<<<grid, b256, 0, stream>>>(A, lda, K, W, ldw, bias, resid, ldr,
                                               Cf, Cb, ldc, gelu);
    };
    auto attn = [&](const bf16* q, int ldq, const bf16* k, int ldk,
                    const bf16* v, int ldv, bf16* o, int ldo, int delta) {
        attn_mfma_kernel<<<dim3((M_TOK / 64) * NH), b256, 0, stream>>>(
            q, ldq, k, ldk, v, ldv, o, ldo, delta);
    };

    embed_h_kernel<<<(M_TOK * D_MODEL) / 256, b256, 0, stream>>>(x, tok_emb, pos_emb, h);
    embed_p_kernel<<<(PREFIX * D_MODEL) / 256, b256, 0, stream>>>(x, tok_emb, pos_emb, eb);

    // ---- cross-attention block ----
    ln_kernel<<<M_TOK, b256, 0, stream>>>(h, ca_ln_g, ca_ln_b, xnb);
    gemm(xnb, D_MODEL, D_MODEL, ca_wq, INNER, nullptr, nullptr, 0,
         nullptr, qb, INNER, M_TOK, INNER, 0);
    gemm(eb, D_MODEL, D_MODEL, ca_wkv, 2 * INNER, nullptr, nullptr, 0,
         nullptr, kvb, 2 * INNER, PREFIX, 2 * INNER, 0);
    gemm(xnb, D_MODEL, D_MODEL, ca_wkv, 2 * INNER, nullptr, nullptr, 0,
         nullptr, kvb + (size_t)PREFIX * 2 * INNER, 2 * INNER, M_TOK, 2 * INNER, 0);
    attn(qb, INNER, kvb, 2 * INNER, kvb + INNER, 2 * INNER, aob, INNER, PREFIX);
    gemm(aob, INNER, INNER, ca_wo, D_MODEL, ca_bo, h, D_MODEL,
         h, nullptr, D_MODEL, M_TOK, D_MODEL, 0);

    // ---- cross ffwd ----
    ln_kernel<<<M_TOK, b256, 0, stream>>>(h, cf_ln_g, cf_ln_b, xnb);
    gemm(xnb, D_MODEL, D_MODEL, cf_w1, FF_DIM, nullptr, nullptr, 0,
         nullptr, ffb, FF_DIM, M_TOK, FF_DIM, 1);
    gemm(ffb, FF_DIM, FF_DIM, cf_w2, D_MODEL, nullptr, h, D_MODEL,
         h, nullptr, D_MODEL, M_TOK, D_MODEL, 0);

    // ---- 4 self-attention transformer blocks ----
    for (int l = 0; l < DEPTH; l++) {
        ln_kernel<<<M_TOK, b256, 0, stream>>>(h, la_ln_g + l * D_MODEL,
                                              la_ln_b + l * D_MODEL, xnb);
        gemm(xnb, D_MODEL, D_MODEL, la_wqkv + (size_t)l * D_MODEL * 3 * INNER, 3 * INNER,
             nullptr, nullptr, 0, nullptr, qkvb, 3 * INNER, M_TOK, 3 * INNER, 0);
        attn(qkvb, 3 * INNER, qkvb + INNER, 3 * INNER,
             qkvb + 2 * INNER, 3 * INNER, aob, INNER, 0);
        gemm(aob, INNER, INNER, la_wo + (size_t)l * INNER * D_MODEL, D_MODEL,
             nullptr, h, D_MODEL, h, nullptr, D_MODEL, M_TOK, D_MODEL, 0);
        ln_kernel<<<M_TOK, b256, 0, stream>>>(h, lf_ln_g + l * D_MODEL,
                                              lf_ln_b + l * D_MODEL, xnb);
        gemm(xnb, D_MODEL, D_MODEL, lf_w1 + (size_t)l * D_MODEL * FF_DIM, FF_DIM,
             nullptr, nullptr, 0, nullptr, ffb, FF_DIM, M_TOK, FF_DIM, 1);
        gemm(ffb, FF_DIM, FF_DIM, lf_w2 + (size_t)l * FF_DIM * D_MODEL, D_MODEL,
             nullptr, h, D_MODEL, h, (l == DEPTH - 1) ? hb : nullptr, D_MODEL,
             M_TOK, D_MODEL, 0);
    }

    // ---- logits head ----
    gemm(hb, D_MODEL, D_MODEL, w_logits, VOCAB, nullptr, nullptr, 0,
         out, nullptr, VOCAB, M_TOK, VOCAB, 0);
}